// Round 2
// baseline (357.570 us; speedup 1.0000x reference)
//
#include <hip/hip_runtime.h>

#define NA 4096
#define NB 4096
#define DIM 256
#define DK 64
#define PSTR 72   // pbuf row stride (bf16 elements)

typedef __attribute__((ext_vector_type(8))) short bf16x8;
typedef __attribute__((ext_vector_type(4))) float f32x4;
typedef __attribute__((ext_vector_type(4))) unsigned short us4;
typedef __attribute__((ext_vector_type(4))) int i32x4;

static __device__ __forceinline__ float bf2f(unsigned short u) {
    union { unsigned int u; float f; } x;
    x.u = ((unsigned int)u) << 16;
    return x.f;
}
static __device__ __forceinline__ unsigned short f2bf(float f) {
    union { float f; unsigned int u; } x;
    x.f = f;
    unsigned int r = x.u + 0x7fffu + ((x.u >> 16) & 1u);
    return (unsigned short)(r >> 16);
}

// 8 fp32 -> split bf16 (hi + lo correction), hi+lo carries ~16 mantissa bits
static __device__ __forceinline__ void split8(const float* __restrict__ p,
                                              bf16x8& hi, bf16x8& lo) {
    f32x4 u = *(const f32x4*)p;
    f32x4 v = *(const f32x4*)(p + 4);
    #pragma unroll
    for (int r = 0; r < 4; ++r) {
        unsigned short h0 = f2bf(u[r]);
        hi[r] = (short)h0;  lo[r] = (short)f2bf(u[r] - bf2f(h0));
        unsigned short h1 = f2bf(v[r]);
        hi[r + 4] = (short)h1;  lo[r + 4] = (short)f2bf(v[r] - bf2f(h1));
    }
}

// ---------------------------------------------------------------------------
// Projections from fp32 inputs, fp32-accurate via 3-term split-bf16 MFMA:
//   X·W^T ≈ xh·wh + xl·wh + xh·wl   (xl·wl dropped, ~2^-18 rel)
// mat 0: q  -> q_hi + q_lo  [4096,256] bf16 pair (2-term QK later)
// mat 1: k  -> k_hi         [4096,256] bf16
// mat 2: v  -> vt           [256,4096] bf16 transposed (PV B-frags contiguous)
// ---------------------------------------------------------------------------
__global__ __launch_bounds__(256) void proj_kernel(
    const float* __restrict__ a_z,
    const float* __restrict__ bv_z,
    const float* __restrict__ Wq,
    const float* __restrict__ Wk,
    const float* __restrict__ Wv,
    unsigned short* __restrict__ qhi,
    unsigned short* __restrict__ qlo,
    unsigned short* __restrict__ khi,
    unsigned short* __restrict__ vtout)
{
    const int mat = blockIdx.z;
    const float* __restrict__ X = (mat == 0) ? a_z : bv_z;
    const float* __restrict__ W = (mat == 0) ? Wq : ((mat == 1) ? Wk : Wv);

    const int tid  = threadIdx.x;
    const int wv   = tid >> 6;
    const int lane = tid & 63;
    const int c    = lane & 15;
    const int quad = lane >> 4;
    const int n0 = blockIdx.x * 64;
    const int j0 = blockIdx.y * 64 + wv * 16;

    f32x4 acc[4];
    #pragma unroll
    for (int nt = 0; nt < 4; ++nt) acc[nt] = (f32x4){0.f, 0.f, 0.f, 0.f};

    #pragma unroll
    for (int ki = 0; ki < 8; ++ki) {
        const int i0 = ki * 32 + quad * 8;
        bf16x8 wh, wl;
        split8(W + (j0 + c) * DIM + i0, wh, wl);
        #pragma unroll
        for (int nt = 0; nt < 4; ++nt) {
            bf16x8 xh, xl;
            split8(X + (n0 + nt * 16 + c) * DIM + i0, xh, xl);
            acc[nt] = __builtin_amdgcn_mfma_f32_16x16x32_bf16(xh, wh, acc[nt], 0, 0, 0);
            acc[nt] = __builtin_amdgcn_mfma_f32_16x16x32_bf16(xl, wh, acc[nt], 0, 0, 0);
            acc[nt] = __builtin_amdgcn_mfma_f32_16x16x32_bf16(xh, wl, acc[nt], 0, 0, 0);
        }
    }

    // C/D layout: col = lane&15 (j), row = quad*4 + r (n)
    if (mat == 0) {
        #pragma unroll
        for (int nt = 0; nt < 4; ++nt)
            #pragma unroll
            for (int r = 0; r < 4; ++r) {
                const int idx = (n0 + nt * 16 + quad * 4 + r) * DIM + j0 + c;
                unsigned short h = f2bf(acc[nt][r]);
                qhi[idx] = h;
                qlo[idx] = f2bf(acc[nt][r] - bf2f(h));
            }
    } else if (mat == 1) {
        #pragma unroll
        for (int nt = 0; nt < 4; ++nt)
            #pragma unroll
            for (int r = 0; r < 4; ++r)
                khi[(n0 + nt * 16 + quad * 4 + r) * DIM + j0 + c] = f2bf(acc[nt][r]);
    } else {
        #pragma unroll
        for (int nt = 0; nt < 4; ++nt) {
            us4 p;
            #pragma unroll
            for (int r = 0; r < 4; ++r) p[r] = f2bf(acc[nt][r]);
            *(us4*)(vtout + (j0 + c) * NB + n0 + nt * 16 + quad * 4) = p;
        }
    }
}

// ---------------------------------------------------------------------------
// Fused attention. 256 blocks x 16 a-rows, 512 threads = 4 heads x 2 b-halves.
// No barriers in the K-loop (pbuf is wave-private; weight/mask read direct
// from global as float4/int4 — fp32 weight, no staging).
// S^T = K·(Qhi)^T + K·(Qlo)^T ; P = exp(clip(S/8 + w)) masked (scores in
// [-10,10] -> no online max). influence == 1.0 analytically.
// ---------------------------------------------------------------------------
__global__ __launch_bounds__(512, 2) void attn_kernel(
    const unsigned short* __restrict__ qhg,
    const unsigned short* __restrict__ qlg,
    const unsigned short* __restrict__ kg,
    const unsigned short* __restrict__ vtg,
    const float* __restrict__ wg,
    const int* __restrict__ mg,
    float* __restrict__ outp)
{
    __shared__ unsigned short pbuf[8][16 * PSTR];
    __shared__ float numbuf[8][16][65];
    __shared__ float denbuf[8][16];

    const int tid  = threadIdx.x;
    const int wv   = tid >> 6;
    const int lane = tid & 63;
    const int c    = lane & 15;
    const int quad = lane >> 4;
    const int head = wv & 3;
    const int half = wv >> 2;
    const int a0   = blockIdx.x * 16;

    bf16x8 qh[2], ql[2];
    #pragma unroll
    for (int ks = 0; ks < 2; ++ks) {
        qh[ks] = *(const bf16x8*)(qhg + (a0 + c) * DIM + head * DK + ks * 32 + quad * 8);
        ql[ks] = *(const bf16x8*)(qlg + (a0 + c) * DIM + head * DK + ks * 32 + quad * 8);
    }

    f32x4 num[4];
    #pragma unroll
    for (int nt = 0; nt < 4; ++nt) num[nt] = (f32x4){0.f, 0.f, 0.f, 0.f};
    float den = 0.0f;

    for (int it = 0; it < 32; ++it) {
        const int b0 = (it * 2 + half) * 64;

        // all global loads issued up front (k, v, w, m independent of MFMAs)
        bf16x8 kf[4][2];
        #pragma unroll
        for (int bt = 0; bt < 4; ++bt)
            #pragma unroll
            for (int ks = 0; ks < 2; ++ks)
                kf[bt][ks] = *(const bf16x8*)(kg + (b0 + bt * 16 + c) * DIM + head * DK + ks * 32 + quad * 8);

        f32x4 wf[4];
        i32x4 mf[4];
        #pragma unroll
        for (int bt = 0; bt < 4; ++bt) {
            const size_t off = (size_t)(a0 + c) * NB + b0 + bt * 16 + quad * 4;
            wf[bt] = *(const f32x4*)(wg + off);
            mf[bt] = *(const i32x4*)(mg + off);
        }

        bf16x8 vf[4][2];
        #pragma unroll
        for (int nt = 0; nt < 4; ++nt)
            #pragma unroll
            for (int ks2 = 0; ks2 < 2; ++ks2)
                vf[nt][ks2] = *(const bf16x8*)(vtg + (head * DK + nt * 16 + c) * NB + b0 + ks2 * 32 + quad * 8);

        // S^T[b][a]: A = K rows (m=b), B = Q rows (n=a); 2-term q split
        f32x4 S[4];
        #pragma unroll
        for (int bt = 0; bt < 4; ++bt) {
            f32x4 s = (f32x4){0.f, 0.f, 0.f, 0.f};
            s = __builtin_amdgcn_mfma_f32_16x16x32_bf16(kf[bt][0], qh[0], s, 0, 0, 0);
            s = __builtin_amdgcn_mfma_f32_16x16x32_bf16(kf[bt][1], qh[1], s, 0, 0, 0);
            s = __builtin_amdgcn_mfma_f32_16x16x32_bf16(kf[bt][0], ql[0], s, 0, 0, 0);
            s = __builtin_amdgcn_mfma_f32_16x16x32_bf16(kf[bt][1], ql[1], s, 0, 0, 0);
            S[bt] = s;
        }

        // elementwise: lane holds (a = c, b = bt*16 + quad*4 + r)
        #pragma unroll
        for (int bt = 0; bt < 4; ++bt) {
            us4 p;
            #pragma unroll
            for (int r = 0; r < 4; ++r) {
                float t = fmaf(S[bt][r], 0.125f, wf[bt][r]);
                t = __builtin_amdgcn_fmed3f(t, -10.0f, 10.0f);
                t = mf[bt][r] ? t : -10.0f;
                float e = exp2f(t * 1.4426950408889634f);
                p[r] = f2bf(e);
                den += bf2f(p[r]);   // den consistent with bf16-rounded P
            }
            *(us4*)(&pbuf[wv][c * PSTR + bt * 16 + quad * 4]) = p;
        }

        // PV: A-frags from wave-private P (no barrier), B-frags from vt
        bf16x8 pf[2];
        #pragma unroll
        for (int ks2 = 0; ks2 < 2; ++ks2)
            pf[ks2] = *(const bf16x8*)(&pbuf[wv][c * PSTR + ks2 * 32 + quad * 8]);
        #pragma unroll
        for (int nt = 0; nt < 4; ++nt) {
            num[nt] = __builtin_amdgcn_mfma_f32_16x16x32_bf16(pf[0], vf[nt][0], num[nt], 0, 0, 0);
            num[nt] = __builtin_amdgcn_mfma_f32_16x16x32_bf16(pf[1], vf[nt][1], num[nt], 0, 0, 0);
        }
    }

    // den: sum across quads (lanes with same a = lane&15)
    den += __shfl_xor(den, 16, 64);
    den += __shfl_xor(den, 32, 64);
    if (lane < 16) denbuf[wv][lane] = den;

    // num C-layout: col = lane&15 = dk-sub, row = quad*4+r = a
    #pragma unroll
    for (int nt = 0; nt < 4; ++nt)
        #pragma unroll
        for (int r = 0; r < 4; ++r)
            numbuf[wv][quad * 4 + r][nt * 16 + c] = num[nt][r];
    __syncthreads();

    for (int e = tid; e < 16 * 64; e += 512) {
        const int a = e >> 6, dd = e & 63;
        float s = 0.0f;
        #pragma unroll
        for (int hh = 0; hh < 4; ++hh) {
            float nsum = numbuf[hh][a][dd] + numbuf[hh + 4][a][dd];
            float dsum = denbuf[hh][a] + denbuf[hh + 4][a];
            s += nsum / dsum;
        }
        outp[(a0 + a) * DK + dd] = 0.25f * s;
    }
    // influence == 1.0 exactly (softmax rows sum to 1; mean over heads of 1)
    if (tid < 16) outp[NA * DK + a0 + tid] = 1.0f;
}

extern "C" void kernel_launch(void* const* d_in, const int* in_sizes, int n_in,
                              void* d_out, int out_size, void* d_ws, size_t ws_size,
                              hipStream_t stream) {
    const float* a_z = (const float*)d_in[0];
    const float* bv  = (const float*)d_in[1];
    const int* mask  = (const int*)d_in[2];
    const float* wgt = (const float*)d_in[3];
    const float* Wq  = (const float*)d_in[4];
    const float* Wk  = (const float*)d_in[5];
    const float* Wv  = (const float*)d_in[6];
    float* out = (float*)d_out;

    unsigned short* qhi = (unsigned short*)d_ws;           // [4096][256]
    unsigned short* qlo = qhi + NA * DIM;                  // [4096][256]
    unsigned short* khi = qlo + NA * DIM;                  // [4096][256]
    unsigned short* vt  = khi + NB * DIM;                  // [256][4096]

    proj_kernel<<<dim3(64, 4, 3), 256, 0, stream>>>(a_z, bv, Wq, Wk, Wv, qhi, qlo, khi, vt);
    attn_kernel<<<dim3(256), 512, 0, stream>>>(qhi, qlo, khi, vt, wgt, mask, out);
}